// Round 14
// baseline (565.749 us; speedup 1.0000x reference)
//
#include <hip/hip_runtime.h>
#include <hip/hip_bf16.h>
#include <cstdint>
#include <cstdio>
#include <type_traits>

// B=16, S=2048, H=1024, D=16, T=5;  M = B*S = 32768, N = 2H = 2048, K = 1024.
// Stack scan: 32 chunks x 64 steps; affine composition.
//   top[j] = top_local[j] + sum_d coef[j,d]*st_start[d], coef = p*Apre (h-independent)
// R14: correction fused into k5 (k3p deleted). sstart+coef live in the Abf
// region (dead after k1); sle/atot live in d_out's final region (consumed by
// k2b before k5 writes final). k5 reads the f32 hidden residual directly.

typedef float f32x4 __attribute__((ext_vector_type(4)));
typedef __bf16 bf8v __attribute__((ext_vector_type(8)));

// d_ws byte offsets
#define WS_ABF   0ULL                 // 67,108,864  hidden bf16 (k1 A); after k1: sstart+coef
#define WS_SST   0ULL                 // sstart f32: 33,554,432 B   (overlays Abf, post-k1)
#define WS_COEF  33554432ULL          // coef  f32:  2,097,152 B    (overlays Abf, post-k1)
#define WS_WBF   67108864ULL          // 4,194,304   W_proj bf16
#define WS_PROJ  71303168ULL          // 134,217,728 proj = [h_all|v_all]; v_all later = tops_local
#define WS_OP4   205520896ULL         // 524,288     op_probs padded float4
#define WS_WP    206045184ULL         // 4,194,304   interleaved (w,p) f32
#define WS_NEED  210239488ULL

// d_out float offsets
#define OUT_FINAL 0
#define OUT_STACK 33554432ULL         // (16,16,1024)
#define OUT_PTR   33816576ULL         // (16,16)
#define OUT_TOOLW 33816832ULL         // (16,2048,5)
// scratch inside the final region — consumed BEFORE k5 writes final:
#define SLE_OFF    0ULL               // 16b x 32c x 16d x 1024h f32 (read by k2b)
#define ATOT_OFF   30000000ULL        // 16b x 32c x 16d f32 (read by k2b)

__device__ __forceinline__ float bf2f(unsigned short u) {
    union { unsigned int i; float f; } v; v.i = ((unsigned int)u) << 16; return v.f;
}
__device__ __forceinline__ unsigned short f2bf(float f) {
    __hip_bfloat16 h = __float2bfloat16(f);
    return __builtin_bit_cast(unsigned short, h);
}
template<int C>
__device__ __forceinline__ float fdpp(float x) {
    return __int_as_float(__builtin_amdgcn_mov_dpp(__float_as_int(x), C, 0xF, 0xF, true));
}
__device__ __forceinline__ void gload_lds16(const void* g, void* l) {
    __builtin_amdgcn_global_load_lds(
        (__attribute__((address_space(1))) void*)(uintptr_t)g,
        (__attribute__((address_space(3))) void*)l,
        16, 0, 0);
}

// ---------------------------------------------------------------------------
// k0: hidden -> bf16 (A), W_proj -> bf16 (B), op_probs (f32).
// ---------------------------------------------------------------------------
__global__ __launch_bounds__(256) void k0(const float* __restrict__ hid,
                                          const float* __restrict__ Wp,
                                          const float* __restrict__ Wop,
                                          const float* __restrict__ bop,
                                          unsigned short* __restrict__ Abf,
                                          unsigned short* __restrict__ Wbf,
                                          float4* __restrict__ op4)
{
    const int bid = blockIdx.x, tid = threadIdx.x;
    if (bid < 8192) {
        const int wid = tid >> 6, lane = tid & 63;
        const int row = bid * 4 + wid;
        const float* hrow = hid + (size_t)row * 1024 + lane * 16;
        float xs[16];
        #pragma unroll
        for (int j = 0; j < 4; ++j) {
            float4 t = *(const float4*)(hrow + j * 4);
            xs[j*4+0] = t.x; xs[j*4+1] = t.y; xs[j*4+2] = t.z; xs[j*4+3] = t.w;
        }
        unsigned short us[16];
        #pragma unroll
        for (int j = 0; j < 16; ++j) us[j] = f2bf(xs[j]);
        uint4 ulo, uhi;
        ulo.x = (unsigned)us[0]  | ((unsigned)us[1]  << 16);
        ulo.y = (unsigned)us[2]  | ((unsigned)us[3]  << 16);
        ulo.z = (unsigned)us[4]  | ((unsigned)us[5]  << 16);
        ulo.w = (unsigned)us[6]  | ((unsigned)us[7]  << 16);
        uhi.x = (unsigned)us[8]  | ((unsigned)us[9]  << 16);
        uhi.y = (unsigned)us[10] | ((unsigned)us[11] << 16);
        uhi.z = (unsigned)us[12] | ((unsigned)us[13] << 16);
        uhi.w = (unsigned)us[14] | ((unsigned)us[15] << 16);
        unsigned short* arow = Abf + (size_t)row * 1024 + lane * 16;
        *(uint4*)(arow)     = ulo;
        *(uint4*)(arow + 8) = uhi;
        float pt[3] = {0.f, 0.f, 0.f};
        #pragma unroll
        for (int o = 0; o < 3; ++o) {
            const float* wrow = Wop + o * 1024 + lane * 16;
            #pragma unroll
            for (int j = 0; j < 4; ++j) {
                float4 t = *(const float4*)(wrow + j * 4);
                pt[o] += xs[j*4+0]*t.x + xs[j*4+1]*t.y + xs[j*4+2]*t.z + xs[j*4+3]*t.w;
            }
        }
        #pragma unroll
        for (int o = 0; o < 3; ++o)
            #pragma unroll
            for (int m = 32; m >= 1; m >>= 1) pt[o] += __shfl_xor(pt[o], m);
        if (lane == 0) {
            float l0 = pt[0] + bop[0], l1 = pt[1] + bop[1], l2 = pt[2] + bop[2];
            float mx = fmaxf(l0, fmaxf(l1, l2));
            float e0 = expf(l0 - mx), e1 = expf(l1 - mx), e2 = expf(l2 - mx);
            float inv = 1.0f / (e0 + e1 + e2);
            float4 r; r.x = e0 * inv; r.y = e1 * inv; r.z = e2 * inv; r.w = 0.f;
            op4[row] = r;
        }
    } else {
        const int b2 = bid - 8192;
        const size_t base = (size_t)b2 * 2048 + tid * 8;
        float4 a = *(const float4*)(Wp + base);
        float4 b = *(const float4*)(Wp + base + 4);
        unsigned short vs[8] = { f2bf(a.x), f2bf(a.y), f2bf(a.z), f2bf(a.w),
                                 f2bf(b.x), f2bf(b.y), f2bf(b.z), f2bf(b.w) };
        uint4 u;
        u.x = (unsigned)vs[0] | ((unsigned)vs[1] << 16);
        u.y = (unsigned)vs[2] | ((unsigned)vs[3] << 16);
        u.z = (unsigned)vs[4] | ((unsigned)vs[5] << 16);
        u.w = (unsigned)vs[6] | ((unsigned)vs[7] << 16);
        *(uint4*)(Wbf + base) = u;
    }
}

// ---------------------------------------------------------------------------
// k1: blocks 0..3 pointer scan (4 batches/wave, DPP, wp+atot out);
//     blocks 4..1027 bf16 MFMA GEMM 256x256, BK=64, 8 waves, counted
//     vmcnt(8); intra-tile: read-AHEAD of the next quadrant's operands
//     before each MFMA cluster (DS latency hides under MFMA), raw barriers.
// ---------------------------------------------------------------------------
__global__ __launch_bounds__(512, 2) void k1(const unsigned short* __restrict__ Abf,
                                             const unsigned short* __restrict__ Wbf,
                                             const float* __restrict__ bproj,
                                             unsigned short* __restrict__ proj,
                                             const float4* __restrict__ op4,
                                             float* __restrict__ wpbuf,
                                             float* __restrict__ out)
{
    __shared__ uint4 sm[8192];   // 128 KiB
    const int bid = blockIdx.x, tid = threadIdx.x;

    if (bid < 4) {
        const int bbase = bid * 4;               // 4 batches per block (wave 0)
        #pragma unroll
        for (int i = 0; i < 16; ++i)
            sm[tid + i * 512] = ((const uint4*)op4)[(size_t)bbase * 2048 + tid + i * 512];
        __syncthreads();
        if (tid >= 64) return;                   // wave 0 only
        __builtin_amdgcn_s_setprio(1);
        const int lane = tid, d = lane & 15, b4 = lane >> 4;
        const int b = bbase + b4;
        const float4* smf = (const float4*)sm + (size_t)b4 * 2048;
        float* wpb  = wpbuf + (size_t)b * 65536;           // (w,p) pairs
        float* atot = out + ATOT_OFF + (size_t)b * 512;
        const float probe = (float)d;
        const bool ror1_is_push = (fdpp<0x121>(probe) == (float)((d + 15) & 15));
        float p = (d == 0) ? 1.0f : 0.0f;
        float Apre = 1.0f;

        auto run = [&](auto pushc, auto popc) {
            constexpr int PU = decltype(pushc)::value;
            constexpr int PO = decltype(popc)::value;
            float4 o0 = smf[0], o1 = smf[1];
            #pragma unroll 4
            for (int s = 0; s < 2048; ++s) {
                float4 o2 = smf[(s + 2 < 2048) ? (s + 2) : 2047];
                const float push = o0.x, pop = o0.y, nop = o0.z;
                const float ppush = fdpp<PU>(p);
                const float ppop  = fdpp<PO>(p);
                const float w = push * ppush;
                float lin = push * ppush + pop * ppop + nop * p;
                float x2 = lin * lin;
                float x5 = x2 * x2 * lin;
                float sum = x5;
                sum += fdpp<0x128>(sum);
                sum += fdpp<0x124>(sum);
                sum += fdpp<0x122>(sum);
                sum += fdpp<0x121>(sum);
                float pn = x5 * __builtin_amdgcn_rcpf(sum + 1e-8f);
                const float om = 1.0f - w;
                Apre = ((s & 63) == 0) ? om : Apre * om;
                float2 wp; wp.x = w; wp.y = pn;
                *(float2*)(wpb + ((size_t)s * 16 + d) * 2) = wp;
                if ((s & 63) == 63) atot[(s >> 6) * 16 + d] = Apre;
                p = pn;
                o0 = o1; o1 = o2;
            }
        };
        if (ror1_is_push)
            run(std::integral_constant<int,0x121>{}, std::integral_constant<int,0x12F>{});
        else
            run(std::integral_constant<int,0x12F>{}, std::integral_constant<int,0x121>{});
        out[OUT_PTR + (size_t)b * 16 + d] = p;
        return;
    }

    // ---- GEMM: proj[m,n] = sum_k A[m,k]*W[n,k] + b_proj[n] ----
    const int li = bid - 4;                   // 0..1023
    const int xcd = li & 7, j = li >> 3;
    const int gm = xcd * 16 + (j >> 3);       // 128 m-tiles, 16 per XCD
    const int gn = j & 7;                     // 8 n-tiles, fastest
    const int wid = tid >> 6, lane = tid & 63;
    const int wm = wid >> 2, wn = wid & 3;    // 2x4 waves of 128x64 output
    const size_t row0 = (size_t)gm * 256;
    const size_t col0 = (size_t)gn * 256;
    char* smc = (char*)sm;
    const char* Ab = (const char*)Abf;
    const char* Bb = (const char*)Wbf;
    const int laneR = lane & 15;
    const int laneK = (lane >> 4) * 16;

    f32x4 acc[8][4];
    const f32x4 z = {0.f, 0.f, 0.f, 0.f};
    #pragma unroll
    for (int i = 0; i < 8; ++i)
        #pragma unroll
        for (int jj = 0; jj < 4; ++jj) acc[i][jj] = z;

    // slot layout (64 KiB each): A-half0 @0, A-half1 @16K, B-half0 @32K, B-half1 @48K
    // swz(x) = x ^ ((x>>7 & 7) << 4); linear LDS dest, inverse-swizzled source
    auto STAGE = [&](int kt, int slot) {
        #pragma unroll
        for (int hf = 0; hf < 4; ++hf) {
            #pragma unroll
            for (int i = 0; i < 2; ++i) {
                const int idx  = i * 512 + tid;          // 0..1023 (x16B = 16 KiB half)
                const int off  = idx * 16;
                const int soff = off ^ (((off >> 7) & 7) << 4);
                const int irow = soff >> 7;              // 0..127 within half
                const int colb = soff & 127;
                const char* src = (hf < 2)
                    ? (Ab + (row0 + (size_t)(hf * 128 + irow)) * 2048 + (size_t)kt * 128 + colb)
                    : (Bb + (col0 + (size_t)((hf - 2) * 128 + irow)) * 2048 + (size_t)kt * 128 + colb);
                gload_lds16(src, smc + slot * 65536 + hf * 16384 + (i * 512 + wid * 64) * 16);
            }
        }
    };

    STAGE(0, 0);
    int cur = 0;
    #pragma unroll 1
    for (int kt = 0; kt < 16; ++kt) {
        if (kt < 15) {
            STAGE(kt + 1, cur ^ 1);            // 8 younger loads; stay in flight below
            asm volatile("s_waitcnt vmcnt(8)" ::: "memory");   // tile kt landed
        } else {
            asm volatile("s_waitcnt vmcnt(0)" ::: "memory");
        }
        __builtin_amdgcn_sched_barrier(0);
        __builtin_amdgcn_s_barrier();          // all waves' tile-kt data resident
        const char* Abase = smc + cur * 65536 + wm * 16384;
        const char* Bbase = smc + cur * 65536 + 32768 + (wn >> 1) * 16384;
        const int bro = (wn & 1) * 64;

        bf8v af[4][2], afh[4][2], bfr[4][2];
        // ---- read q1 operands (A mh0 + B nh0) AND q2's B (nh1) up front ----
        #pragma unroll
        for (int m2 = 0; m2 < 4; ++m2)
            #pragma unroll
            for (int kk = 0; kk < 2; ++kk) {
                int byt = (m2 * 16 + laneR) * 128 + kk * 64 + laneK;
                byt ^= ((byt >> 7) & 7) << 4;
                af[m2][kk] = *(const bf8v*)(Abase + byt);
            }
        #pragma unroll
        for (int n2 = 0; n2 < 4; ++n2)
            #pragma unroll
            for (int kk = 0; kk < 2; ++kk) {
                int byt = (bro + n2 * 16 + laneR) * 128 + kk * 64 + laneK;
                byt ^= ((byt >> 7) & 7) << 4;
                bfr[n2][kk] = *(const bf8v*)(Bbase + byt);
            }
        // ---- P1: MFMA quad (mh0,nh0) — waits only af+bfr[0..1] ----
        __builtin_amdgcn_s_setprio(1);
        #pragma unroll
        for (int m2 = 0; m2 < 4; ++m2)
            #pragma unroll
            for (int n2 = 0; n2 < 2; ++n2)
                #pragma unroll
                for (int kk = 0; kk < 2; ++kk)
                    acc[m2][n2] = __builtin_amdgcn_mfma_f32_16x16x32_bf16(af[m2][kk], bfr[n2][kk], acc[m2][n2], 0, 0, 0);
        __builtin_amdgcn_s_setprio(0);
        __builtin_amdgcn_s_barrier();
        // ---- read A mh1 (for q3/q4) before q2's MFMA ----
        #pragma unroll
        for (int m2 = 0; m2 < 4; ++m2)
            #pragma unroll
            for (int kk = 0; kk < 2; ++kk) {
                int byt = ((64 + m2 * 16 + laneR)) * 128 + kk * 64 + laneK;
                byt ^= ((byt >> 7) & 7) << 4;
                afh[m2][kk] = *(const bf8v*)(Abase + byt);
            }
        // ---- P2: MFMA quad (mh0,nh1) — bfr[2..3] landed during P1 ----
        __builtin_amdgcn_s_setprio(1);
        #pragma unroll
        for (int m2 = 0; m2 < 4; ++m2)
            #pragma unroll
            for (int n2 = 2; n2 < 4; ++n2)
                #pragma unroll
                for (int kk = 0; kk < 2; ++kk)
                    acc[m2][n2] = __builtin_amdgcn_mfma_f32_16x16x32_bf16(af[m2][kk], bfr[n2][kk], acc[m2][n2], 0, 0, 0);
        __builtin_amdgcn_s_setprio(0);
        __builtin_amdgcn_s_barrier();
        // ---- P3: MFMA quad (mh1,nh1) — afh landed during P2 ----
        __builtin_amdgcn_s_setprio(1);
        #pragma unroll
        for (int m2 = 0; m2 < 4; ++m2)
            #pragma unroll
            for (int n2 = 2; n2 < 4; ++n2)
                #pragma unroll
                for (int kk = 0; kk < 2; ++kk)
                    acc[4 + m2][n2] = __builtin_amdgcn_mfma_f32_16x16x32_bf16(afh[m2][kk], bfr[n2][kk], acc[4 + m2][n2], 0, 0, 0);
        __builtin_amdgcn_s_setprio(0);
        __builtin_amdgcn_s_barrier();
        // ---- P4: MFMA quad (mh1,nh0) — operands live ----
        __builtin_amdgcn_s_setprio(1);
        #pragma unroll
        for (int m2 = 0; m2 < 4; ++m2)
            #pragma unroll
            for (int n2 = 0; n2 < 2; ++n2)
                #pragma unroll
                for (int kk = 0; kk < 2; ++kk)
                    acc[4 + m2][n2] = __builtin_amdgcn_mfma_f32_16x16x32_bf16(afh[m2][kk], bfr[n2][kk], acc[4 + m2][n2], 0, 0, 0);
        __builtin_amdgcn_s_setprio(0);
        __builtin_amdgcn_s_barrier();          // buf cur reads done -> next STAGE may overwrite cur^1
        cur ^= 1;
    }
    // epilogue: C/D layout col = lane&15, row = (lane>>4)*4 + j
    #pragma unroll
    for (int mr = 0; mr < 8; ++mr) {
        const int rloc = wm * 128 + mr * 16 + ((lane >> 4) * 4);
        #pragma unroll
        for (int nr = 0; nr < 4; ++nr) {
            const size_t col = col0 + wn * 64 + nr * 16 + laneR;
            const float bias = bproj[col];
            #pragma unroll
            for (int jj = 0; jj < 4; ++jj)
                proj[(row0 + rloc + jj) * 2048 + col] = f2bf(acc[mr][nr][jj] + bias);
        }
    }
}

// ---------------------------------------------------------------------------
// k2: single scan pass with ZERO start. Emits top_local (bf16, overwrites
// proj v_all in place) + chunk-end st_local (sle, all 32 chunks).
// grid 2048 = 16 b x 32 c x 4 hg; thread owns one h, 16 d-slots.
// ---------------------------------------------------------------------------
__global__ __launch_bounds__(256) void k2(unsigned short* __restrict__ proj,
                                          const float* __restrict__ wpbuf,
                                          float* __restrict__ sle)
{
    __shared__ unsigned short vlds[2][4096];
    const int bid = blockIdx.x, tid = threadIdx.x;
    const int hg = bid & 3, c = (bid >> 2) & 31, b = bid >> 7;
    const int wid = tid >> 6;
    const char* vbase = (const char*)proj +
        ((size_t)(b * 2048 + c * 64) * 2048 + 1024 + hg * 256) * 2;
    const float* wpb = wpbuf + ((size_t)b * 2048 + c * 64) * 32;
    unsigned short* topb = proj + ((size_t)b * 2048 + c * 64) * 2048 + 1024 + hg * 256 + tid;

    float st[16];
    #pragma unroll
    for (int d = 0; d < 16; ++d) st[d] = 0.f;

    auto STAGE = [&](int sc, int buf) {
        #pragma unroll
        for (int i = 0; i < 2; ++i) {
            const int g = i * 256 + tid;
            gload_lds16(vbase + (size_t)(sc * 16 + (g >> 5)) * 4096 + (g & 31) * 16,
                        (char*)vlds + buf * 8192 + (i * 256 + wid * 64) * 16);
        }
    };
    STAGE(0, 0);
    __syncthreads();
    for (int sc = 0; sc < 4; ++sc) {
        const int cur = sc & 1;
        if (sc < 3) STAGE(sc + 1, cur ^ 1);   // reads rows sc+1; writes below hit rows sc only
        const unsigned short* vl = vlds[cur];
        #pragma unroll 4
        for (int ls = 0; ls < 16; ++ls) {
            const float v = bf2f(vl[ls * 256 + tid]);
            const float4* wp4 = (const float4*)(wpb + (size_t)(sc * 16 + ls) * 32);
            float t0 = 0.f, t1 = 0.f;
            #pragma unroll
            for (int k = 0; k < 8; ++k) {
                float4 q = wp4[k];
                st[2*k]   = fmaf(q.x, v - st[2*k],   st[2*k]);
                st[2*k+1] = fmaf(q.z, v - st[2*k+1], st[2*k+1]);
                t0 = fmaf(q.y, st[2*k],   t0);
                t1 = fmaf(q.w, st[2*k+1], t1);
            }
            topb[(size_t)(sc * 16 + ls) * 2048] = f2bf(t0 + t1);
        }
        __syncthreads();
    }
    float* so = sle + ((size_t)b * 32 + c) * 16 * 1024 + hg * 256 + tid;
    #pragma unroll
    for (int d = 0; d < 16; ++d) so[(size_t)d * 1024] = st[d];
}

// ---------------------------------------------------------------------------
// k2c: coef[j,d] = p[j,d] * prod_{i<=j}(1-w[i,d])  (h-independent, 2 MB).
// grid 512 = b*32+c; lanes 0..15 each own one d; serial over 64 steps.
// ---------------------------------------------------------------------------
__global__ __launch_bounds__(64) void k2c(const float* __restrict__ wpbuf,
                                          float* __restrict__ coefb)
{
    const int bid = blockIdx.x, tid = threadIdx.x;
    if (tid >= 16) return;
    const int b = bid >> 5, c = bid & 31;
    const float* wp = wpbuf + (size_t)b * 65536 + (size_t)c * 64 * 32 + tid * 2;
    float* co = coefb + (size_t)bid * 1024 + tid;
    float A = 1.f;
    #pragma unroll 8
    for (int j = 0; j < 64; ++j) {
        float2 q = *(const float2*)(wp + j * 32);
        A *= (1.f - q.x);
        co[j * 16] = q.y * A;
    }
}

// ---------------------------------------------------------------------------
// k2b: prefix over chunks -> sstart; also emits the final stack output
// (A31*sstart31 + sle31). grid 1024 = 16 b x 16 d x 4 hg; thread owns one h.
// ---------------------------------------------------------------------------
__global__ __launch_bounds__(256) void k2b(const float* __restrict__ sle,
                                           const float* __restrict__ atot,
                                           float* __restrict__ sstart,
                                           float* __restrict__ out)
{
    const int bid = blockIdx.x, tid = threadIdx.x;
    const int hg = bid & 3, d = (bid >> 2) & 15, b = bid >> 6;
    const int h = hg * 256 + tid;
    const float* sb = sle    + ((size_t)b * 512 + d) * 1024 + h;
    float*       so = sstart + ((size_t)b * 512 + d) * 1024 + h;
    const float* ab = atot + (size_t)b * 512 + d;
    float st = 0.f;
    #pragma unroll 4
    for (int c = 0; c < 31; ++c) {
        so[(size_t)c * 16384] = st;
        st = fmaf(ab[c * 16], st, sb[(size_t)c * 16384]);
    }
    so[31ull * 16384] = st;
    const float fin = fmaf(ab[31 * 16], st, sb[31ull * 16384]);
    out[OUT_STACK + ((size_t)b * 16 + d) * 1024 + h] = fin;
}

// ---------------------------------------------------------------------------
// k5: per (b,s) row: correct tops (rank-16, f32), tool softmax, apply tools,
// residual (f32 hidden), LayerNorm. Row index XCD-grouped so the 64 rows of
// one (b,c) share the L2-resident sstart slice.
// ---------------------------------------------------------------------------
__global__ __launch_bounds__(256) void k5(const unsigned short* __restrict__ proj,
                                          const float* __restrict__ hid,
                                          const float* __restrict__ Wtool,
                                          const float* __restrict__ btool,
                                          const float* __restrict__ gamma,
                                          const float* __restrict__ beta,
                                          const float* __restrict__ sstart,
                                          const float* __restrict__ coefb,
                                          float* __restrict__ out)
{
    __shared__ float red[4][8];
    // bijective remap: i = (g&7) + 8*(r + 64*(g>>3)); all 64 rows of group g
    // land on XCD g&7 (blockIdx round-robins XCDs mod 8).
    const int i = blockIdx.x;
    const int xcd = i & 7, t0 = i >> 3;
    const int r = t0 & 63, gh = t0 >> 6;
    const int g = gh * 8 + xcd;                // (b*32 + c) in [0,512)
    const int row = g * 64 + r;
    const int tid = threadIdx.x;
    const int wid = tid >> 6, lane = tid & 63;
    const int k0i = tid * 4;
    uint2 hu = *(const uint2*)(proj + (size_t)row * 2048 + k0i);
    float hh[4];
    hh[0] = bf2f(hu.x & 0xffff); hh[1] = bf2f(hu.x >> 16);
    hh[2] = bf2f(hu.y & 0xffff); hh[3] = bf2f(hu.y >> 16);
    uint2 tu = *(const uint2*)(proj + (size_t)row * 2048 + 1024 + k0i);
    float xs[4];
    xs[0] = bf2f(tu.x & 0xffff); xs[1] = bf2f(tu.x >> 16);
    xs[2] = bf2f(tu.y & 0xffff); xs[3] = bf2f(tu.y >> 16);
    // rank-16 correction: xs += coef[g][r][d] * sstart[g][d][h]
    {
        const float* cof = coefb + (size_t)g * 1024 + r * 16;
        const float* ssb = sstart + (size_t)g * 16384 + k0i;
        #pragma unroll
        for (int d = 0; d < 16; ++d) {
            const float cf = cof[d];
            float4 sv = *(const float4*)(ssb + (size_t)d * 1024);
            xs[0] = fmaf(cf, sv.x, xs[0]);
            xs[1] = fmaf(cf, sv.y, xs[1]);
            xs[2] = fmaf(cf, sv.z, xs[2]);
            xs[3] = fmaf(cf, sv.w, xs[3]);
        }
    }
    float4 hd4 = *(const float4*)(hid + (size_t)row * 1024 + k0i);
    float hds[4] = {hd4.x, hd4.y, hd4.z, hd4.w};
    float pt[5];
    #pragma unroll
    for (int t = 0; t < 5; ++t) {
        float4 wv = *(const float4*)(Wtool + t * 1024 + k0i);
        pt[t] = hh[0]*wv.x + hh[1]*wv.y + hh[2]*wv.z + hh[3]*wv.w;
    }
    #pragma unroll
    for (int t = 0; t < 5; ++t)
        #pragma unroll
        for (int m = 32; m >= 1; m >>= 1) pt[t] += __shfl_xor(pt[t], m);
    if (lane == 0) {
        #pragma unroll
        for (int t = 0; t < 5; ++t) red[wid][t] = pt[t];
    }
    __syncthreads();
    float tw[5];
    {
        float lg[5];
        #pragma unroll
        for (int t = 0; t < 5; ++t)
            lg[t] = red[0][t] + red[1][t] + red[2][t] + red[3][t] + btool[t];
        float mx = fmaxf(fmaxf(fmaxf(lg[0], lg[1]), fmaxf(lg[2], lg[3])), lg[4]);
        float se = 0.f;
        #pragma unroll
        for (int t = 0; t < 5; ++t) { tw[t] = expf(lg[t] - mx); se += tw[t]; }
        float inv = 1.0f / se;
        #pragma unroll
        for (int t = 0; t < 5; ++t) tw[t] *= inv;
    }
    if (tid < 5) out[OUT_TOOLW + (size_t)row * 5 + tid] = tw[tid];
    float cj[4];
    #pragma unroll
    for (int j = 0; j < 4; ++j) {
        const float x = xs[j];
        const float rl = fmaxf(x, 0.f);
        const float gl = 0.5f * x * (1.f + erff(x * 0.70710678118654752f));
        const float th = tanhf(x);
        const float sg = 1.f / (1.f + expf(-x));
        const float pr = rl*tw[0] + gl*tw[1] + th*tw[2] + sg*tw[3] + x*tw[4];
        cj[j] = hh[j] + pr + hds[j];
    }
    float s1 = cj[0] + cj[1] + cj[2] + cj[3];
    float s2 = cj[0]*cj[0] + cj[1]*cj[1] + cj[2]*cj[2] + cj[3]*cj[3];
    #pragma unroll
    for (int m = 32; m >= 1; m >>= 1) { s1 += __shfl_xor(s1, m); s2 += __shfl_xor(s2, m); }
    __syncthreads();
    if (lane == 0) { red[wid][0] = s1; red[wid][1] = s2; }
    __syncthreads();
    const float S1 = red[0][0] + red[1][0] + red[2][0] + red[3][0];
    const float S2 = red[0][1] + red[1][1] + red[2][1] + red[3][1];
    const float mu = S1 * (1.f / 1024.f);
    const float var = S2 * (1.f / 1024.f) - mu * mu;
    const float rstd = rsqrtf(var + 1e-5f);
    float4 g4 = *(const float4*)(gamma + k0i);
    float4 b4 = *(const float4*)(beta + k0i);
    float4 res;
    res.x = (cj[0] - mu) * rstd * g4.x + b4.x;
    res.y = (cj[1] - mu) * rstd * g4.y + b4.y;
    res.z = (cj[2] - mu) * rstd * g4.z + b4.z;
    res.w = (cj[3] - mu) * rstd * g4.w + b4.w;
    *(float4*)(out + (size_t)row * 1024 + k0i) = res;
}

extern "C" void kernel_launch(void* const* d_in, const int* in_sizes, int n_in,
                              void* d_out, int out_size, void* d_ws, size_t ws_size,
                              hipStream_t stream)
{
    if (ws_size < WS_NEED) {
        fprintf(stderr, "kernel_launch: ws_size %zu < required %llu\n",
                ws_size, (unsigned long long)WS_NEED);
        return;
    }
    const float* hid = (const float*)d_in[0];
    const float* Wp  = (const float*)d_in[1];
    const float* bp  = (const float*)d_in[2];
    const float* Wop = (const float*)d_in[3];
    const float* bop = (const float*)d_in[4];
    const float* Wtl = (const float*)d_in[5];
    const float* btl = (const float*)d_in[6];
    const float* gam = (const float*)d_in[7];
    const float* bet = (const float*)d_in[8];
    float* out = (float*)d_out;
    char* ws = (char*)d_ws;
    unsigned short* Abf  = (unsigned short*)(ws + WS_ABF);   // hidden bf16 (k1 A)
    unsigned short* Wbf  = (unsigned short*)(ws + WS_WBF);
    unsigned short* proj = (unsigned short*)(ws + WS_PROJ);
    float4* op4 = (float4*)(ws + WS_OP4);
    float* wpbuf  = (float*)(ws + WS_WP);
    float* sstart = (float*)(ws + WS_SST);    // overlays Abf after k1
    float* coefb  = (float*)(ws + WS_COEF);   // overlays Abf after k1
    float* sle    = out + SLE_OFF;            // consumed by k2b before k5
    float* atot   = out + ATOT_OFF;           // consumed by k2b before k5

    k0 <<<9216, 256, 0, stream>>>(hid, Wp, Wop, bop, Abf, Wbf, op4);
    k1 <<<1028, 512, 0, stream>>>(Abf, Wbf, bp, proj, op4, wpbuf, out);
    k2 <<<2048, 256, 0, stream>>>(proj, wpbuf, sle);
    k2c<<<512,  64,  0, stream>>>(wpbuf, coefb);
    k2b<<<1024, 256, 0, stream>>>(sle, atot, sstart, out);
    k5 <<<32768, 256, 0, stream>>>(proj, hid, Wtl, btl, gam, bet, sstart, coefb, out);
}

// Round 15
// 444.972 us; speedup vs baseline: 1.2714x; 1.2714x over previous
//
#include <hip/hip_runtime.h>
#include <hip/hip_bf16.h>
#include <cstdint>
#include <cstdio>
#include <type_traits>

// B=16, S=2048, H=1024, D=16, T=5;  M = B*S = 32768, N = 2H = 2048, K = 1024.
// Stack scan: 32 chunks x 64 steps; affine composition.
//   top[j] = top_local[j] + sum_d coef[j,d]*st_start[d], coef = p*Apre (h-independent)

typedef float f32x4 __attribute__((ext_vector_type(4)));
typedef __bf16 bf8v __attribute__((ext_vector_type(8)));

// d_ws byte offsets
#define WS_ABF   0ULL                 // 67,108,864  hidden bf16 (k5 reads it)
#define WS_WBF   67108864ULL          // 4,194,304   W_proj bf16
#define WS_PROJ  71303168ULL          // 134,217,728 proj = [h_all|v_all]; v_all later = tops
#define WS_OP4   205520896ULL         // 524,288     op_probs padded float4
#define WS_WP    206045184ULL         // 4,194,304   interleaved (w,p) f32
#define WS_NEED  210239488ULL

// d_out float offsets
#define OUT_FINAL 0
#define OUT_STACK 33554432ULL         // (16,16,1024)
#define OUT_PTR   33816576ULL         // (16,16)
#define OUT_TOOLW 33816832ULL         // (16,2048,5)
// scratch inside the (not-yet-written) final region (floats):
#define SLE_OFF    0ULL               // 16b x 32c x 16d x 1024h = 8,388,608 floats
#define SSTART_OFF 9437184ULL         // same shape: chunk-start states
#define COEF_OFF   18874368ULL        // 16b x 32c x 64j x 16d = 524,288 floats
#define ATOT_OFF   30000000ULL        // 16b x 32c x 16d = 8192 floats

__device__ __forceinline__ float bf2f(unsigned short u) {
    union { unsigned int i; float f; } v; v.i = ((unsigned int)u) << 16; return v.f;
}
__device__ __forceinline__ unsigned short f2bf(float f) {
    __hip_bfloat16 h = __float2bfloat16(f);
    return __builtin_bit_cast(unsigned short, h);
}
template<int C>
__device__ __forceinline__ float fdpp(float x) {
    return __int_as_float(__builtin_amdgcn_mov_dpp(__float_as_int(x), C, 0xF, 0xF, true));
}
__device__ __forceinline__ void gload_lds16(const void* g, void* l) {
    __builtin_amdgcn_global_load_lds(
        (__attribute__((address_space(1))) void*)(uintptr_t)g,
        (__attribute__((address_space(3))) void*)l,
        16, 0, 0);
}

// ---------------------------------------------------------------------------
// k0: hidden -> bf16 (A), W_proj -> bf16 (B), op_probs (f32).
// ---------------------------------------------------------------------------
__global__ __launch_bounds__(256) void k0(const float* __restrict__ hid,
                                          const float* __restrict__ Wp,
                                          const float* __restrict__ Wop,
                                          const float* __restrict__ bop,
                                          unsigned short* __restrict__ Abf,
                                          unsigned short* __restrict__ Wbf,
                                          float4* __restrict__ op4)
{
    const int bid = blockIdx.x, tid = threadIdx.x;
    if (bid < 8192) {
        const int wid = tid >> 6, lane = tid & 63;
        const int row = bid * 4 + wid;
        const float* hrow = hid + (size_t)row * 1024 + lane * 16;
        float xs[16];
        #pragma unroll
        for (int j = 0; j < 4; ++j) {
            float4 t = *(const float4*)(hrow + j * 4);
            xs[j*4+0] = t.x; xs[j*4+1] = t.y; xs[j*4+2] = t.z; xs[j*4+3] = t.w;
        }
        unsigned short us[16];
        #pragma unroll
        for (int j = 0; j < 16; ++j) us[j] = f2bf(xs[j]);
        uint4 ulo, uhi;
        ulo.x = (unsigned)us[0]  | ((unsigned)us[1]  << 16);
        ulo.y = (unsigned)us[2]  | ((unsigned)us[3]  << 16);
        ulo.z = (unsigned)us[4]  | ((unsigned)us[5]  << 16);
        ulo.w = (unsigned)us[6]  | ((unsigned)us[7]  << 16);
        uhi.x = (unsigned)us[8]  | ((unsigned)us[9]  << 16);
        uhi.y = (unsigned)us[10] | ((unsigned)us[11] << 16);
        uhi.z = (unsigned)us[12] | ((unsigned)us[13] << 16);
        uhi.w = (unsigned)us[14] | ((unsigned)us[15] << 16);
        unsigned short* arow = Abf + (size_t)row * 1024 + lane * 16;
        *(uint4*)(arow)     = ulo;
        *(uint4*)(arow + 8) = uhi;
        float pt[3] = {0.f, 0.f, 0.f};
        #pragma unroll
        for (int o = 0; o < 3; ++o) {
            const float* wrow = Wop + o * 1024 + lane * 16;
            #pragma unroll
            for (int j = 0; j < 4; ++j) {
                float4 t = *(const float4*)(wrow + j * 4);
                pt[o] += xs[j*4+0]*t.x + xs[j*4+1]*t.y + xs[j*4+2]*t.z + xs[j*4+3]*t.w;
            }
        }
        #pragma unroll
        for (int o = 0; o < 3; ++o)
            #pragma unroll
            for (int m = 32; m >= 1; m >>= 1) pt[o] += __shfl_xor(pt[o], m);
        if (lane == 0) {
            float l0 = pt[0] + bop[0], l1 = pt[1] + bop[1], l2 = pt[2] + bop[2];
            float mx = fmaxf(l0, fmaxf(l1, l2));
            float e0 = expf(l0 - mx), e1 = expf(l1 - mx), e2 = expf(l2 - mx);
            float inv = 1.0f / (e0 + e1 + e2);
            float4 r; r.x = e0 * inv; r.y = e1 * inv; r.z = e2 * inv; r.w = 0.f;
            op4[row] = r;
        }
    } else {
        const int b2 = bid - 8192;
        const size_t base = (size_t)b2 * 2048 + tid * 8;
        float4 a = *(const float4*)(Wp + base);
        float4 b = *(const float4*)(Wp + base + 4);
        unsigned short vs[8] = { f2bf(a.x), f2bf(a.y), f2bf(a.z), f2bf(a.w),
                                 f2bf(b.x), f2bf(b.y), f2bf(b.z), f2bf(b.w) };
        uint4 u;
        u.x = (unsigned)vs[0] | ((unsigned)vs[1] << 16);
        u.y = (unsigned)vs[2] | ((unsigned)vs[3] << 16);
        u.z = (unsigned)vs[4] | ((unsigned)vs[5] << 16);
        u.w = (unsigned)vs[6] | ((unsigned)vs[7] << 16);
        *(uint4*)(Wbf + base) = u;
    }
}

// ---------------------------------------------------------------------------
// k1: blocks 0..3 pointer scan (4 batches per wave, 16-lane rows, all lanes
//     active, branch-specialized DPP direction, coef folded in);
//     blocks 4..1027 bf16 MFMA GEMM (R7-exact: 256x256, BK=64, 8 waves,
//     counted vmcnt(8), 4 MFMA quadrant phases, raw barriers, setprio).
// ---------------------------------------------------------------------------
__global__ __launch_bounds__(512, 2) void k1(const unsigned short* __restrict__ Abf,
                                             const unsigned short* __restrict__ Wbf,
                                             const float* __restrict__ bproj,
                                             unsigned short* __restrict__ proj,
                                             const float4* __restrict__ op4,
                                             float* __restrict__ wpbuf,
                                             float* __restrict__ out)
{
    __shared__ uint4 sm[8192];   // 128 KiB
    const int bid = blockIdx.x, tid = threadIdx.x;

    if (bid < 4) {
        const int bbase = bid * 4;               // 4 batches per block (wave 0)
        #pragma unroll
        for (int i = 0; i < 16; ++i)
            sm[tid + i * 512] = ((const uint4*)op4)[(size_t)bbase * 2048 + tid + i * 512];
        __syncthreads();
        if (tid >= 64) return;                   // wave 0 only
        __builtin_amdgcn_s_setprio(1);
        const int lane = tid, d = lane & 15, b4 = lane >> 4;
        const int b = bbase + b4;
        const float4* smf = (const float4*)sm + (size_t)b4 * 2048;
        float* wpb  = wpbuf + (size_t)b * 65536;           // (w,p) pairs
        float* cob  = out + COEF_OFF + (size_t)b * 32768;  // coef
        float* atot = out + ATOT_OFF + (size_t)b * 512;
        const float probe = (float)d;
        const bool ror1_is_push = (fdpp<0x121>(probe) == (float)((d + 15) & 15));
        float p = (d == 0) ? 1.0f : 0.0f;
        float Apre = 1.0f;

        auto run = [&](auto pushc, auto popc) {
            constexpr int PU = decltype(pushc)::value;
            constexpr int PO = decltype(popc)::value;
            float4 o0 = smf[0], o1 = smf[1];
            #pragma unroll 4
            for (int s = 0; s < 2048; ++s) {
                float4 o2 = smf[(s + 2 < 2048) ? (s + 2) : 2047];
                const float push = o0.x, pop = o0.y, nop = o0.z;
                const float ppush = fdpp<PU>(p);
                const float ppop  = fdpp<PO>(p);
                const float w = push * ppush;
                float lin = push * ppush + pop * ppop + nop * p;
                float x2 = lin * lin;
                float x5 = x2 * x2 * lin;
                float sum = x5;
                sum += fdpp<0x128>(sum);
                sum += fdpp<0x124>(sum);
                sum += fdpp<0x122>(sum);
                sum += fdpp<0x121>(sum);
                float pn = x5 * __builtin_amdgcn_rcpf(sum + 1e-8f);
                const float om = 1.0f - w;
                Apre = ((s & 63) == 0) ? om : Apre * om;
                float2 wp; wp.x = w; wp.y = pn;
                *(float2*)(wpb + ((size_t)s * 16 + d) * 2) = wp;
                cob[(size_t)s * 16 + d] = pn * Apre;
                if ((s & 63) == 63) atot[(s >> 6) * 16 + d] = Apre;
                p = pn;
                o0 = o1; o1 = o2;
            }
        };
        if (ror1_is_push)
            run(std::integral_constant<int,0x121>{}, std::integral_constant<int,0x12F>{});
        else
            run(std::integral_constant<int,0x12F>{}, std::integral_constant<int,0x121>{});
        out[OUT_PTR + (size_t)b * 16 + d] = p;
        return;
    }

    // ---- GEMM: proj[m,n] = sum_k A[m,k]*W[n,k] + b_proj[n] ----
    const int li = bid - 4;                   // 0..1023
    const int xcd = li & 7, j = li >> 3;
    const int gm = xcd * 16 + (j >> 3);       // 128 m-tiles, 16 per XCD
    const int gn = j & 7;                     // 8 n-tiles, fastest
    const int wid = tid >> 6, lane = tid & 63;
    const int wm = wid >> 2, wn = wid & 3;    // 2x4 waves of 128x64 output
    const size_t row0 = (size_t)gm * 256;
    const size_t col0 = (size_t)gn * 256;
    char* smc = (char*)sm;
    const char* Ab = (const char*)Abf;
    const char* Bb = (const char*)Wbf;
    const int laneR = lane & 15;
    const int laneK = (lane >> 4) * 16;

    f32x4 acc[8][4];
    const f32x4 z = {0.f, 0.f, 0.f, 0.f};
    #pragma unroll
    for (int i = 0; i < 8; ++i)
        #pragma unroll
        for (int jj = 0; jj < 4; ++jj) acc[i][jj] = z;

    // slot layout (64 KiB each): A-half0 @0, A-half1 @16K, B-half0 @32K, B-half1 @48K
    // swz(x) = x ^ ((x>>7 & 7) << 4); linear LDS dest, inverse-swizzled source
    auto STAGE = [&](int kt, int slot) {
        #pragma unroll
        for (int hf = 0; hf < 4; ++hf) {
            #pragma unroll
            for (int i = 0; i < 2; ++i) {
                const int idx  = i * 512 + tid;          // 0..1023 (x16B = 16 KiB half)
                const int off  = idx * 16;
                const int soff = off ^ (((off >> 7) & 7) << 4);
                const int irow = soff >> 7;              // 0..127 within half
                const int colb = soff & 127;
                const char* src = (hf < 2)
                    ? (Ab + (row0 + (size_t)(hf * 128 + irow)) * 2048 + (size_t)kt * 128 + colb)
                    : (Bb + (col0 + (size_t)((hf - 2) * 128 + irow)) * 2048 + (size_t)kt * 128 + colb);
                gload_lds16(src, smc + slot * 65536 + hf * 16384 + (i * 512 + wid * 64) * 16);
            }
        }
    };

    STAGE(0, 0);
    int cur = 0;
    #pragma unroll 1
    for (int kt = 0; kt < 16; ++kt) {
        if (kt < 15) {
            STAGE(kt + 1, cur ^ 1);            // 8 younger loads; stay in flight below
            asm volatile("s_waitcnt vmcnt(8)" ::: "memory");   // tile kt landed
        } else {
            asm volatile("s_waitcnt vmcnt(0)" ::: "memory");
        }
        __builtin_amdgcn_sched_barrier(0);
        __builtin_amdgcn_s_barrier();          // all waves' tile-kt data resident
        const char* Abase = smc + cur * 65536 + wm * 16384;
        const char* Bbase = smc + cur * 65536 + 32768 + (wn >> 1) * 16384;
        const int bro = (wn & 1) * 64;

        bf8v af[4][2], bfr[4][2];
        // ---- P1: read A(mh0)+B(nh0); MFMA quad (mh0,nh0) ----
        #pragma unroll
        for (int m2 = 0; m2 < 4; ++m2)
            #pragma unroll
            for (int kk = 0; kk < 2; ++kk) {
                int byt = (m2 * 16 + laneR) * 128 + kk * 64 + laneK;
                byt ^= ((byt >> 7) & 7) << 4;
                af[m2][kk] = *(const bf8v*)(Abase + byt);
            }
        #pragma unroll
        for (int n2 = 0; n2 < 2; ++n2)
            #pragma unroll
            for (int kk = 0; kk < 2; ++kk) {
                int byt = (bro + n2 * 16 + laneR) * 128 + kk * 64 + laneK;
                byt ^= ((byt >> 7) & 7) << 4;
                bfr[n2][kk] = *(const bf8v*)(Bbase + byt);
            }
        __builtin_amdgcn_s_setprio(1);
        #pragma unroll
        for (int m2 = 0; m2 < 4; ++m2)
            #pragma unroll
            for (int n2 = 0; n2 < 2; ++n2)
                #pragma unroll
                for (int kk = 0; kk < 2; ++kk)
                    acc[m2][n2] = __builtin_amdgcn_mfma_f32_16x16x32_bf16(af[m2][kk], bfr[n2][kk], acc[m2][n2], 0, 0, 0);
        __builtin_amdgcn_s_setprio(0);
        __builtin_amdgcn_s_barrier();
        // ---- P2: read B(nh1); MFMA quad (mh0,nh1) ----
        #pragma unroll
        for (int n2 = 2; n2 < 4; ++n2)
            #pragma unroll
            for (int kk = 0; kk < 2; ++kk) {
                int byt = (bro + n2 * 16 + laneR) * 128 + kk * 64 + laneK;
                byt ^= ((byt >> 7) & 7) << 4;
                bfr[n2][kk] = *(const bf8v*)(Bbase + byt);
            }
        __builtin_amdgcn_s_setprio(1);
        #pragma unroll
        for (int m2 = 0; m2 < 4; ++m2)
            #pragma unroll
            for (int n2 = 2; n2 < 4; ++n2)
                #pragma unroll
                for (int kk = 0; kk < 2; ++kk)
                    acc[m2][n2] = __builtin_amdgcn_mfma_f32_16x16x32_bf16(af[m2][kk], bfr[n2][kk], acc[m2][n2], 0, 0, 0);
        __builtin_amdgcn_s_setprio(0);
        __builtin_amdgcn_s_barrier();
        // ---- P3: read A(mh1); MFMA quad (mh1,nh1) ----
        #pragma unroll
        for (int m2 = 0; m2 < 4; ++m2)
            #pragma unroll
            for (int kk = 0; kk < 2; ++kk) {
                int byt = ((64 + m2 * 16 + laneR)) * 128 + kk * 64 + laneK;
                byt ^= ((byt >> 7) & 7) << 4;
                af[m2][kk] = *(const bf8v*)(Abase + byt);
            }
        __builtin_amdgcn_s_setprio(1);
        #pragma unroll
        for (int m2 = 0; m2 < 4; ++m2)
            #pragma unroll
            for (int n2 = 2; n2 < 4; ++n2)
                #pragma unroll
                for (int kk = 0; kk < 2; ++kk)
                    acc[4 + m2][n2] = __builtin_amdgcn_mfma_f32_16x16x32_bf16(af[m2][kk], bfr[n2][kk], acc[4 + m2][n2], 0, 0, 0);
        __builtin_amdgcn_s_setprio(0);
        __builtin_amdgcn_s_barrier();
        // ---- P4: MFMA quad (mh1,nh0) (operands already live) ----
        __builtin_amdgcn_s_setprio(1);
        #pragma unroll
        for (int m2 = 0; m2 < 4; ++m2)
            #pragma unroll
            for (int n2 = 0; n2 < 2; ++n2)
                #pragma unroll
                for (int kk = 0; kk < 2; ++kk)
                    acc[4 + m2][n2] = __builtin_amdgcn_mfma_f32_16x16x32_bf16(af[m2][kk], bfr[n2][kk], acc[4 + m2][n2], 0, 0, 0);
        __builtin_amdgcn_s_setprio(0);
        __builtin_amdgcn_s_barrier();          // buf cur reads done -> next STAGE may overwrite cur^1
        cur ^= 1;
    }
    // epilogue: C/D layout col = lane&15, row = (lane>>4)*4 + j
    #pragma unroll
    for (int mr = 0; mr < 8; ++mr) {
        const int rloc = wm * 128 + mr * 16 + ((lane >> 4) * 4);
        #pragma unroll
        for (int nr = 0; nr < 4; ++nr) {
            const size_t col = col0 + wn * 64 + nr * 16 + laneR;
            const float bias = bproj[col];
            #pragma unroll
            for (int jj = 0; jj < 4; ++jj)
                proj[(row0 + rloc + jj) * 2048 + col] = f2bf(acc[mr][nr][jj] + bias);
        }
    }
}

// ---------------------------------------------------------------------------
// k2: single scan pass with ZERO start. Emits top_local (bf16, overwrites
// proj v_all in place) + chunk-end st_local (sle, all 32 chunks).
// grid 2048 = 16 b x 32 c x 4 hg; thread owns one h, 16 d-slots.
// ---------------------------------------------------------------------------
__global__ __launch_bounds__(256) void k2(unsigned short* __restrict__ proj,
                                          const float* __restrict__ wpbuf,
                                          float* __restrict__ sle)
{
    __shared__ unsigned short vlds[2][4096];
    const int bid = blockIdx.x, tid = threadIdx.x;
    const int hg = bid & 3, c = (bid >> 2) & 31, b = bid >> 7;
    const int wid = tid >> 6;
    const char* vbase = (const char*)proj +
        ((size_t)(b * 2048 + c * 64) * 2048 + 1024 + hg * 256) * 2;
    const float* wpb = wpbuf + ((size_t)b * 2048 + c * 64) * 32;
    unsigned short* topb = proj + ((size_t)b * 2048 + c * 64) * 2048 + 1024 + hg * 256 + tid;

    float st[16];
    #pragma unroll
    for (int d = 0; d < 16; ++d) st[d] = 0.f;

    auto STAGE = [&](int sc, int buf) {
        #pragma unroll
        for (int i = 0; i < 2; ++i) {
            const int g = i * 256 + tid;
            gload_lds16(vbase + (size_t)(sc * 16 + (g >> 5)) * 4096 + (g & 31) * 16,
                        (char*)vlds + buf * 8192 + (i * 256 + wid * 64) * 16);
        }
    };
    STAGE(0, 0);
    __syncthreads();
    for (int sc = 0; sc < 4; ++sc) {
        const int cur = sc & 1;
        if (sc < 3) STAGE(sc + 1, cur ^ 1);   // reads rows sc+1; writes below hit rows sc only
        const unsigned short* vl = vlds[cur];
        #pragma unroll 4
        for (int ls = 0; ls < 16; ++ls) {
            const float v = bf2f(vl[ls * 256 + tid]);
            const float4* wp4 = (const float4*)(wpb + (size_t)(sc * 16 + ls) * 32);
            float t0 = 0.f, t1 = 0.f;
            #pragma unroll
            for (int k = 0; k < 8; ++k) {
                float4 q = wp4[k];
                st[2*k]   = fmaf(q.x, v - st[2*k],   st[2*k]);
                st[2*k+1] = fmaf(q.z, v - st[2*k+1], st[2*k+1]);
                t0 = fmaf(q.y, st[2*k],   t0);
                t1 = fmaf(q.w, st[2*k+1], t1);
            }
            topb[(size_t)(sc * 16 + ls) * 2048] = f2bf(t0 + t1);
        }
        __syncthreads();
    }
    float* so = sle + ((size_t)b * 32 + c) * 16 * 1024 + hg * 256 + tid;
    #pragma unroll
    for (int d = 0; d < 16; ++d) so[(size_t)d * 1024] = st[d];
}

// ---------------------------------------------------------------------------
// k2b: prefix over chunks. grid 1024 = 16 b x 16 d x 4 hg; thread owns one h.
// ---------------------------------------------------------------------------
__global__ __launch_bounds__(256) void k2b(const float* __restrict__ sle,
                                           const float* __restrict__ atot,
                                           float* __restrict__ sstart)
{
    const int bid = blockIdx.x, tid = threadIdx.x;
    const int hg = bid & 3, d = (bid >> 2) & 15, b = bid >> 6;
    const int h = hg * 256 + tid;
    const float* sb = sle    + ((size_t)b * 512 + d) * 1024 + h;
    float*       so = sstart + ((size_t)b * 512 + d) * 1024 + h;
    const float* ab = atot + (size_t)b * 512 + d;
    float st = 0.f;
    #pragma unroll 4
    for (int c = 0; c < 31; ++c) {
        so[(size_t)c * 16384] = st;
        st = fmaf(ab[c * 16], st, sb[(size_t)c * 16384]);
    }
    so[31ull * 16384] = st;
}

// ---------------------------------------------------------------------------
// k3p: streaming correction: tops[64s x 1024h] += coef[64s x 16d] @ sstart[16d x 1024h].
// grid 512 = b*32+c; 256 threads, thread owns 4 h. c==31 also writes final stack.
// ---------------------------------------------------------------------------
__global__ __launch_bounds__(256) void k3p(unsigned short* __restrict__ proj,
                                           const float* __restrict__ sstart,
                                           const float* __restrict__ coefb,
                                           const float* __restrict__ sle,
                                           const float* __restrict__ atot,
                                           float* __restrict__ out)
{
    __shared__ float ssL[16384];   // 64 KiB: sstart[16][1024]
    __shared__ float cofL[1024];   // 4 KiB:  coef[64][16]
    const int bid = blockIdx.x, tid = threadIdx.x;
    const int b = bid >> 5, c = bid & 31;
    {
        const float4* ssg = (const float4*)(sstart + (size_t)bid * 16384);
        #pragma unroll
        for (int i = 0; i < 16; ++i)
            ((float4*)ssL)[i * 256 + tid] = ssg[i * 256 + tid];
        ((float4*)cofL)[tid] = ((const float4*)(coefb + (size_t)bid * 1024))[tid];
    }
    __syncthreads();
    const int h0 = tid * 4;
    float ss[16][4];
    #pragma unroll
    for (int d = 0; d < 16; ++d) {
        float4 t = *(const float4*)(ssL + d * 1024 + h0);
        ss[d][0] = t.x; ss[d][1] = t.y; ss[d][2] = t.z; ss[d][3] = t.w;
    }
    unsigned short* trow = proj + ((size_t)(b * 2048 + c * 64)) * 2048 + 1024 + h0;
    #pragma unroll 2
    for (int s = 0; s < 64; ++s) {
        uint2 tu = *(const uint2*)(trow + (size_t)s * 2048);
        float a0 = bf2f(tu.x & 0xffff), a1 = bf2f(tu.x >> 16);
        float a2 = bf2f(tu.y & 0xffff), a3 = bf2f(tu.y >> 16);
        #pragma unroll
        for (int d = 0; d < 16; ++d) {
            const float cf = cofL[s * 16 + d];   // broadcast read
            a0 = fmaf(cf, ss[d][0], a0);
            a1 = fmaf(cf, ss[d][1], a1);
            a2 = fmaf(cf, ss[d][2], a2);
            a3 = fmaf(cf, ss[d][3], a3);
        }
        uint2 o;
        o.x = (unsigned)f2bf(a0) | ((unsigned)f2bf(a1) << 16);
        o.y = (unsigned)f2bf(a2) | ((unsigned)f2bf(a3) << 16);
        *(uint2*)(trow + (size_t)s * 2048) = o;
    }
    if (c == 31) {
        #pragma unroll
        for (int d = 0; d < 16; ++d) {
            float4 sl = *(const float4*)(sle + (((size_t)b * 32 + 31) * 16 + d) * 1024 + h0);
            const float A = atot[(size_t)b * 512 + 31 * 16 + d];
            float4 r;
            r.x = fmaf(A, ss[d][0], sl.x); r.y = fmaf(A, ss[d][1], sl.y);
            r.z = fmaf(A, ss[d][2], sl.z); r.w = fmaf(A, ss[d][3], sl.w);
            *(float4*)(out + OUT_STACK + ((size_t)b * 16 + d) * 1024 + h0) = r;
        }
    }
}

// ---------------------------------------------------------------------------
// k5: epilogue per (b,s) row: tool softmax, apply tools, residual, LayerNorm.
// ---------------------------------------------------------------------------
__global__ __launch_bounds__(256) void k5(const unsigned short* __restrict__ proj,
                                          const unsigned short* __restrict__ hidbf,
                                          const float* __restrict__ Wtool,
                                          const float* __restrict__ btool,
                                          const float* __restrict__ gamma,
                                          const float* __restrict__ beta,
                                          float* __restrict__ out)
{
    __shared__ float red[4][8];
    const int row = blockIdx.x, tid = threadIdx.x;
    const int wid = tid >> 6, lane = tid & 63;
    const int k0i = tid * 4;
    uint2 hu = *(const uint2*)(proj + (size_t)row * 2048 + k0i);
    float hh[4];
    hh[0] = bf2f(hu.x & 0xffff); hh[1] = bf2f(hu.x >> 16);
    hh[2] = bf2f(hu.y & 0xffff); hh[3] = bf2f(hu.y >> 16);
    uint2 tu = *(const uint2*)(proj + (size_t)row * 2048 + 1024 + k0i);
    float xs[4];
    xs[0] = bf2f(tu.x & 0xffff); xs[1] = bf2f(tu.x >> 16);
    xs[2] = bf2f(tu.y & 0xffff); xs[3] = bf2f(tu.y >> 16);
    uint2 du = *(const uint2*)(hidbf + (size_t)row * 1024 + k0i);
    float hds[4];
    hds[0] = bf2f(du.x & 0xffff); hds[1] = bf2f(du.x >> 16);
    hds[2] = bf2f(du.y & 0xffff); hds[3] = bf2f(du.y >> 16);
    float pt[5];
    #pragma unroll
    for (int t = 0; t < 5; ++t) {
        float4 wv = *(const float4*)(Wtool + t * 1024 + k0i);
        pt[t] = hh[0]*wv.x + hh[1]*wv.y + hh[2]*wv.z + hh[3]*wv.w;
    }
    #pragma unroll
    for (int t = 0; t < 5; ++t)
        #pragma unroll
        for (int m = 32; m >= 1; m >>= 1) pt[t] += __shfl_xor(pt[t], m);
    if (lane == 0) {
        #pragma unroll
        for (int t = 0; t < 5; ++t) red[wid][t] = pt[t];
    }
    __syncthreads();
    float tw[5];
    {
        float lg[5];
        #pragma unroll
        for (int t = 0; t < 5; ++t)
            lg[t] = red[0][t] + red[1][t] + red[2][t] + red[3][t] + btool[t];
        float mx = fmaxf(fmaxf(fmaxf(lg[0], lg[1]), fmaxf(lg[2], lg[3])), lg[4]);
        float se = 0.f;
        #pragma unroll
        for (int t = 0; t < 5; ++t) { tw[t] = expf(lg[t] - mx); se += tw[t]; }
        float inv = 1.0f / se;
        #pragma unroll
        for (int t = 0; t < 5; ++t) tw[t] *= inv;
    }
    if (tid < 5) out[OUT_TOOLW + (size_t)row * 5 + tid] = tw[tid];
    float cj[4];
    #pragma unroll
    for (int j = 0; j < 4; ++j) {
        const float x = xs[j];
        const float rl = fmaxf(x, 0.f);
        const float gl = 0.5f * x * (1.f + erff(x * 0.70710678118654752f));
        const float th = tanhf(x);
        const float sg = 1.f / (1.f + expf(-x));
        const float pr = rl*tw[0] + gl*tw[1] + th*tw[2] + sg*tw[3] + x*tw[4];
        cj[j] = hh[j] + pr + hds[j];
    }
    float s1 = cj[0] + cj[1] + cj[2] + cj[3];
    float s2 = cj[0]*cj[0] + cj[1]*cj[1] + cj[2]*cj[2] + cj[3]*cj[3];
    #pragma unroll
    for (int m = 32; m >= 1; m >>= 1) { s1 += __shfl_xor(s1, m); s2 += __shfl_xor(s2, m); }
    __syncthreads();
    if (lane == 0) { red[wid][0] = s1; red[wid][1] = s2; }
    __syncthreads();
    const float S1 = red[0][0] + red[1][0] + red[2][0] + red[3][0];
    const float S2 = red[0][1] + red[1][1] + red[2][1] + red[3][1];
    const float mu = S1 * (1.f / 1024.f);
    const float var = S2 * (1.f / 1024.f) - mu * mu;
    const float rstd = rsqrtf(var + 1e-5f);
    float4 g4 = *(const float4*)(gamma + k0i);
    float4 b4 = *(const float4*)(beta + k0i);
    float4 res;
    res.x = (cj[0] - mu) * rstd * g4.x + b4.x;
    res.y = (cj[1] - mu) * rstd * g4.y + b4.y;
    res.z = (cj[2] - mu) * rstd * g4.z + b4.z;
    res.w = (cj[3] - mu) * rstd * g4.w + b4.w;
    *(float4*)(out + (size_t)row * 1024 + k0i) = res;
}

extern "C" void kernel_launch(void* const* d_in, const int* in_sizes, int n_in,
                              void* d_out, int out_size, void* d_ws, size_t ws_size,
                              hipStream_t stream)
{
    if (ws_size < WS_NEED) {
        fprintf(stderr, "kernel_launch: ws_size %zu < required %llu\n",
                ws_size, (unsigned long long)WS_NEED);
        return;
    }
    const float* hid = (const float*)d_in[0];
    const float* Wp  = (const float*)d_in[1];
    const float* bp  = (const float*)d_in[2];
    const float* Wop = (const float*)d_in[3];
    const float* bop = (const float*)d_in[4];
    const float* Wtl = (const float*)d_in[5];
    const float* btl = (const float*)d_in[6];
    const float* gam = (const float*)d_in[7];
    const float* bet = (const float*)d_in[8];
    float* out = (float*)d_out;
    char* ws = (char*)d_ws;
    unsigned short* Abf  = (unsigned short*)(ws + WS_ABF);
    unsigned short* Wbf  = (unsigned short*)(ws + WS_WBF);
    unsigned short* proj = (unsigned short*)(ws + WS_PROJ);
    float4* op4 = (float4*)(ws + WS_OP4);
    float* wpbuf = (float*)(ws + WS_WP);
    float* sle    = out + SLE_OFF;
    float* sstart = out + SSTART_OFF;
    float* coefb  = out + COEF_OFF;
    float* atot   = out + ATOT_OFF;

    k0 <<<9216, 256, 0, stream>>>(hid, Wp, Wop, bop, Abf, Wbf, op4);
    k1 <<<1028, 512, 0, stream>>>(Abf, Wbf, bp, proj, op4, wpbuf, out);
    k2 <<<2048, 256, 0, stream>>>(proj, wpbuf, sle);
    k2b<<<1024, 256, 0, stream>>>(sle, atot, sstart);
    k3p<<<512,  256, 0, stream>>>(proj, sstart, coefb, sle, atot, out);
    k5 <<<32768, 256, 0, stream>>>(proj, Abf, Wtl, btl, gam, bet, out);
}